// Round 8
// baseline (477.797 us; speedup 1.0000x reference)
//
#include <hip/hip_runtime.h>
#include <hip/hip_bf16.h>
#include <math.h>

#define Gn 16000
#define Bn 4096
#define Ln 64
#define Sn 20000
#define NGT 250   // gene tiles of 64

typedef __attribute__((ext_vector_type(8))) short bf16x8;   // 8 bf16 = 4 VGPRs
typedef __attribute__((ext_vector_type(4))) float f32x4;    // MFMA C/D

// ---------- device math helpers ----------

__device__ __forceinline__ float softplus_precise(float z) {
    return fmaxf(z, 0.0f) + log1pf(__expf(-fabsf(z)));
}

// accurate lgamma for z>0 (shift-8 Stirling), used only for the 100-entry table
__device__ __forceinline__ float lgamma_pos8(float z) {
    float p = z * (z + 1.f) * (z + 2.f) * (z + 3.f)
                * (z + 4.f) * (z + 5.f) * (z + 6.f) * (z + 7.f);
    float w = z + 8.f;
    return (w - 0.5f) * __logf(w) - w + 0.9189385332046727f
           + __fdividef(1.0f, 12.0f * w) - __logf(p);
}

__device__ __forceinline__ unsigned short f2bf(float f) {
    union { float f; unsigned int u; } v; v.f = f;
    unsigned int r = v.u + 0x7fff + ((v.u >> 16) & 1);   // RNE
    return (unsigned short)(r >> 16);
}

__device__ __forceinline__ unsigned int pack4(int4 v) {
    return (unsigned int)(v.x & 255) | ((unsigned int)(v.y & 255) << 8)
         | ((unsigned int)(v.z & 255) << 16) | ((unsigned int)(v.w & 255) << 24);
}

// ---------- pack_x: elementwise int32 -> u8 cast, SAME layout ----------
// Pure sequential streaming both sides (262 MB rd + 65 MB wr, fill-class BW).
// x < 100 always, so u8 is lossless. NO transpose (that was R3's mistake).

__global__ __launch_bounds__(256) void pack_x(const int* __restrict__ x,
                                              unsigned char* __restrict__ xt) {
    int idx = blockIdx.x * 256 + threadIdx.x;      // 4,096,000 threads, exact
    const int4* src = (const int4*)x + (size_t)idx * 4;
    int4 a = src[0], b = src[1], c = src[2], d = src[3];
    uint4 P;
    P.x = pack4(a); P.y = pack4(b); P.z = pack4(c); P.w = pack4(d);
    ((uint4*)xt)[idx] = P;
}

// ---------- precompute kernels (verbatim from the 394us-verified build) ----------

__global__ void prep_genes(const float* __restrict__ W,
                           const float* __restrict__ px_o,
                           const float* __restrict__ eta,
                           const float* __restrict__ beta,
                           unsigned short* __restrict__ rhB,
                           float* __restrict__ lsp1,
                           float* __restrict__ lsn,
                           float* __restrict__ eps) {
    int idx = blockIdx.x * 256 + threadIdx.x;   // Gn*64 total, exact
    int g = idx >> 6;
    float bsp = softplus_precise(beta[g]);
    rhB[idx] = f2bf(bsp * softplus_precise(W[idx]));   // W row-major [G][L]
    if (idx < Gn) {
        eps[idx] = softplus_precise(eta[idx]);
        float o = px_o[idx];
        lsp1[idx] = -softplus_precise(-o) - 1.0f;   // log_sigmoid(o) - 1
        lsn[idx]  = -softplus_precise(o);           // log_sigmoid(-o)
    }
}

__global__ void prep_spots(const float* __restrict__ V,
                           const int* __restrict__ ind_x,
                           unsigned short* __restrict__ vBg,
                           float* __restrict__ v64) {
    int idx = blockIdx.x * 256 + threadIdx.x;   // Bn*64 total, exact
    int b = idx >> 6, l = idx & 63;
    int s = ind_x[b];
    vBg[idx] = f2bf(softplus_precise(V[l * Sn + s]));
    if (idx < Bn) {
        int s2 = ind_x[idx];
        v64[idx] = softplus_precise(V[Ln * Sn + s2]);
    }
}

// prior: parallel, atomicAdd into out[Bn+1] (out pre-zeroed by memset)
__global__ void prior_kernel(const float* __restrict__ eta, float* __restrict__ out) {
    int idx = blockIdx.x * 256 + threadIdx.x;
    float s = 0.f;
    if (idx < Gn) {
        float e = eta[idx];
        s = 0.9189385332046727f + 0.5f * e * e;
    }
    #pragma unroll
    for (int off = 32; off; off >>= 1) s += __shfl_xor(s, off, 64);
    __shared__ float red[4];
    if ((threadIdx.x & 63) == 0) red[threadIdx.x >> 6] = s;
    __syncthreads();
    if (threadIdx.x == 0) atomicAdd(&out[Bn + 1], red[0] + red[1] + red[2] + red[3]);
}

// ---------- main kernel: v2 skeleton + u8 x via LDS ----------
//
// term = lgamma(x+r) - lgamma(r) - lgamma(x+1) + x*lsp + r*lsn
//      ~= (s-0.5)ln s - (r-0.5)ln r + x*(lsp-1) + r*lsn - lfact[x],  s = r+x
//
// v9 (vs verified v2): x arrives as u8 (pack_x) -> staged to LDS as a 4 KB
// tile with 4 int4 loads/thread-block-pass: 4x fewer HBM requests AND 4x
// fewer bytes than v2's 16 scalar dwords/thread. A-fragments direct from
// global to registers (v3-verified) -> sA deleted, LDS ~15 KB, 8 blocks/CU.
// Epilogue: xi = byte (ln&3) of dword nb*4+(ln>>2) of row (<=4-way banks).

__global__ __launch_bounds__(256) void main_kernel(
    const unsigned char*  __restrict__ xt,
    const unsigned short* __restrict__ rhB,
    const unsigned short* __restrict__ vBg,
    const float*          __restrict__ v64,
    const float*          __restrict__ lsp1g,
    const float*          __restrict__ lsng,
    const float*          __restrict__ epsg,
    float*                __restrict__ partial) {
    __shared__ __align__(16) unsigned short sB[64][72];   // rh tile [g][l]
    __shared__ __align__(16) unsigned int   sXw[64 * 16]; // 4 KB u8 x tile, dword view
    __shared__ float sv64[64];
    __shared__ float sLsp1[64], sLsn[64], sEps[64];
    __shared__ float lfact[100];
    __shared__ float pred[64];

    const int tid = threadIdx.x;
    const int g0 = blockIdx.x * 64;    // gt-fastest (v2-verified ordering)
    const int b0 = blockIdx.y * 64;

    {   // stage rh tile: 8192B; 256 thr x 16B x 2 row-passes (v2 verbatim)
        int row = tid >> 3;          // 0..31
        int c   = (tid & 7) * 8;     // 0..56 step 8 (shorts)
        *(uint4*)&sB[row][c]      = *(const uint4*)&rhB[(g0 + row) * 64 + c];
        *(uint4*)&sB[row + 32][c] = *(const uint4*)&rhB[(g0 + row + 32) * 64 + c];
    }
    {   // stage x tile: 64 rows x 64 B (u8), one pass: 256 thr x 16 B
        int row = tid >> 2;          // 0..63
        int seg = tid & 3;           // 16-byte segment within row
        uint4 v = *(const uint4*)&xt[(size_t)(b0 + row) * Gn + g0 + seg * 16];
        *(uint4*)&sXw[row * 16 + seg * 4] = v;
    }
    if (tid < 64) {
        sv64[tid]  = v64[b0 + tid];
        sLsp1[tid] = lsp1g[g0 + tid];
        sLsn[tid]  = lsng[g0 + tid];
        sEps[tid]  = epsg[g0 + tid];
    }
    if (tid < 100) lfact[tid] = lgamma_pos8((float)tid + 1.0f);

    const int wave = tid >> 6, lane = tid & 63;
    const int quad = lane >> 4, ln = lane & 15;
    const int mrow = wave * 16 + ln;               // A-fragment m index
    const int xrow = wave * 16 + quad * 4;         // C rows for this lane (4 regs)

    // A-fragments (v tile) direct to registers (v3-verified pattern)
    bf16x8 av0 = *(const bf16x8*)&vBg[(b0 + mrow) * 64 + quad * 8];
    bf16x8 av1 = *(const bf16x8*)&vBg[(b0 + mrow) * 64 + 32 + quad * 8];

    f32x4 acc[4];
    #pragma unroll
    for (int nb = 0; nb < 4; nb++) acc[nb] = (f32x4){0.f, 0.f, 0.f, 0.f};

    __syncthreads();

    // K=64 in two MFMA steps; wave handles m-block=wave, all 4 n-blocks
    #pragma unroll
    for (int kb = 0; kb < 2; kb++) {
        bf16x8 af = kb ? av1 : av0;
        #pragma unroll
        for (int nb = 0; nb < 4; nb++) {
            bf16x8 bfr = *(const bf16x8*)&sB[nb * 16 + ln][kb * 32 + quad * 8];
            acc[nb] = __builtin_amdgcn_mfma_f32_16x16x32_bf16(af, bfr, acc[nb], 0, 0, 0);
        }
    }

    float vvr[4];
    #pragma unroll
    for (int r = 0; r < 4; r++) vvr[r] = sv64[xrow + r];

    const int sh = (ln & 3) * 8;
    float rowpart[4] = {0.f, 0.f, 0.f, 0.f};
    #pragma unroll
    for (int nb = 0; nb < 4; nb++) {
        const float lsp1v = sLsp1[nb * 16 + ln];
        const float lsnv  = sLsn[nb * 16 + ln];
        const float ev    = sEps[nb * 16 + ln];
        #pragma unroll
        for (int r = 0; r < 4; r++) {
            const unsigned int w = sXw[(xrow + r) * 16 + nb * 4 + (ln >> 2)];
            const int   xi = (int)((w >> sh) & 255u);
            const float rr = fmaf(ev, vvr[r], acc[nb][r]);   // + eps*v64, fp32
            const float xf = (float)xi;
            const float s  = rr + xf;
            float t = fmaf(s - 0.5f, __logf(s), -lfact[xi]);
            t = fmaf(-(rr - 0.5f), __logf(rr), t);
            t = fmaf(xf, lsp1v, t);
            t = fmaf(rr, lsnv, t);
            rowpart[r] += t;
        }
    }

    // reduce over the 16 gene-lanes of each quad; stash per-row partials in LDS,
    // then ONE coalesced 256B store per block (no device atomics)
    #pragma unroll
    for (int r = 0; r < 4; r++) {
        float v = rowpart[r];
        v += __shfl_xor(v, 1, 64);
        v += __shfl_xor(v, 2, 64);
        v += __shfl_xor(v, 4, 64);
        v += __shfl_xor(v, 8, 64);
        if (ln == 0) pred[xrow + r] = v;
    }
    __syncthreads();
    if (tid < 64) partial[(size_t)blockIdx.x * Bn + b0 + tid] = pred[tid];
}

// fold partial[NGT][4096] -> out[b] (negated). Direct store, no atomics.
__global__ __launch_bounds__(256) void reduce_kernel(const float* __restrict__ partial,
                                                     float* __restrict__ out) {
    int b = blockIdx.x * 256 + threadIdx.x;
    float s0 = 0.f, s1 = 0.f, s2 = 0.f, s3 = 0.f, s4 = 0.f;
    for (int i = 0; i < NGT; i += 5) {
        s0 += partial[(size_t)(i + 0) * Bn + b];
        s1 += partial[(size_t)(i + 1) * Bn + b];
        s2 += partial[(size_t)(i + 2) * Bn + b];
        s3 += partial[(size_t)(i + 3) * Bn + b];
        s4 += partial[(size_t)(i + 4) * Bn + b];
    }
    out[b] = -(s0 + s1 + s2 + s3 + s4);
}

// ---------- launch ----------

extern "C" void kernel_launch(void* const* d_in, const int* in_sizes, int n_in,
                              void* d_out, int out_size, void* d_ws, size_t ws_size,
                              hipStream_t stream) {
    const int*   x     = (const int*)d_in[0];
    const int*   ind_x = (const int*)d_in[2];
    const float* W     = (const float*)d_in[3];
    const float* px_o  = (const float*)d_in[4];
    const float* eta   = (const float*)d_in[5];
    const float* V     = (const float*)d_in[6];
    const float* beta  = (const float*)d_in[7];
    float* out = (float*)d_out;

    // ws layout (bytes):
    char* wsb = (char*)d_ws;
    unsigned short* rhB  = (unsigned short*)(wsb);                    // Gn*64*2 = 2,048,000
    unsigned short* vBg  = (unsigned short*)(wsb + 2048000);          // Bn*64*2 =   524,288
    float*          v64  = (float*)(wsb + 2572288);                   // Bn*4    =    16,384
    float*          lsp1 = (float*)(wsb + 2588672);                   // Gn*4
    float*          lsn  = (float*)(wsb + 2652672);
    float*          eps  = (float*)(wsb + 2716672);
    float*          part = (float*)(wsb + 2780672);                   // NGT*Bn*4 = 4,096,000
    unsigned char*  xt   = (unsigned char*)(wsb + 6876672);           // Bn*Gn   = 65,536,000

    // zero loss accumulators AND the two scalar slots (prior uses atomicAdd)
    hipMemsetAsync(d_out, 0, (Bn + 2) * sizeof(float), stream);

    pack_x<<<(Bn * Gn / 16) / 256, 256, 0, stream>>>(x, xt);
    prep_genes<<<(Gn * 64) / 256, 256, 0, stream>>>(W, px_o, eta, beta, rhB, lsp1, lsn, eps);
    prep_spots<<<(Bn * 64) / 256, 256, 0, stream>>>(V, ind_x, vBg, v64);
    prior_kernel<<<(Gn + 255) / 256, 256, 0, stream>>>(eta, out);

    dim3 grid(Gn / 64, Bn / 64);   // 250 x 64, gt-fastest (v2-verified ordering)
    main_kernel<<<grid, 256, 0, stream>>>(xt, rhB, vBg, v64, lsp1, lsn, eps, part);

    reduce_kernel<<<Bn / 256, 256, 0, stream>>>(part, out);
}

// Round 9
// 391.189 us; speedup vs baseline: 1.2214x; 1.2214x over previous
//
#include <hip/hip_runtime.h>
#include <hip/hip_bf16.h>
#include <math.h>

#define Gn 16000
#define Bn 4096
#define Ln 64
#define Sn 20000
#define NGT 250           // gene tiles of 64
#define GENE_BLOCKS 4000  // (Gn*64)/256
#define SPOT_BLOCKS 1024  // (Bn*64)/256

typedef __attribute__((ext_vector_type(8))) short bf16x8;   // 8 bf16 = 4 VGPRs
typedef __attribute__((ext_vector_type(4))) float f32x4;    // MFMA C/D

// ---------- device math helpers ----------

__device__ __forceinline__ float softplus_precise(float z) {
    return fmaxf(z, 0.0f) + log1pf(__expf(-fabsf(z)));
}

// accurate lgamma for z>0 (shift-8 Stirling), used only for the 100-entry table
__device__ __forceinline__ float lgamma_pos8(float z) {
    float p = z * (z + 1.f) * (z + 2.f) * (z + 3.f)
                * (z + 4.f) * (z + 5.f) * (z + 6.f) * (z + 7.f);
    float w = z + 8.f;
    return (w - 0.5f) * __logf(w) - w + 0.9189385332046727f
           + __fdividef(1.0f, 12.0f * w) - __logf(p);
}

__device__ __forceinline__ unsigned short f2bf(float f) {
    union { float f; unsigned int u; } v; v.f = f;
    unsigned int r = v.u + 0x7fff + ((v.u >> 16) & 1);   // RNE
    return (unsigned short)(r >> 16);
}

// ---------- fused precompute: genes (+prior partials) | spots ----------
//
// v10: one kernel replaces prep_genes + prep_spots + prior_kernel.
// Blocks [0, GENE_BLOCKS): gene section (math verbatim from verified build);
// blocks 0..63 of it also store a per-block prior partial (plain store, no
// atomics -> idempotent across graph replays, no memset needed anywhere).
// Blocks [GENE_BLOCKS, +SPOT_BLOCKS): spot section, verbatim.

__global__ void prep_fused(const float* __restrict__ W,
                           const float* __restrict__ px_o,
                           const float* __restrict__ eta,
                           const float* __restrict__ beta,
                           const float* __restrict__ V,
                           const int*   __restrict__ ind_x,
                           unsigned short* __restrict__ rhB,
                           float* __restrict__ lsp1,
                           float* __restrict__ lsn,
                           float* __restrict__ eps,
                           unsigned short* __restrict__ vBg,
                           float* __restrict__ v64,
                           float* __restrict__ prior_part) {
    const int bid = blockIdx.x;
    const int tid = threadIdx.x;
    if (bid < GENE_BLOCKS) {
        int idx = bid * 256 + tid;   // Gn*64 total, exact
        int g = idx >> 6;
        float bsp = softplus_precise(beta[g]);
        rhB[idx] = f2bf(bsp * softplus_precise(W[idx]));   // W row-major [G][L]
        float s = 0.f;
        if (idx < Gn) {
            eps[idx] = softplus_precise(eta[idx]);
            float o = px_o[idx];
            lsp1[idx] = -softplus_precise(-o) - 1.0f;   // log_sigmoid(o) - 1
            lsn[idx]  = -softplus_precise(o);           // log_sigmoid(-o)
            float e = eta[idx];
            s = 0.9189385332046727f + 0.5f * e * e;     // -log N(eta;0,1)
        }
        if (bid < 64) {   // only blocks 0..62 have idx<Gn lanes; 63 writes 0
            #pragma unroll
            for (int off = 32; off; off >>= 1) s += __shfl_xor(s, off, 64);
            __shared__ float red[4];
            if ((tid & 63) == 0) red[tid >> 6] = s;
            __syncthreads();
            if (tid == 0) prior_part[bid] = red[0] + red[1] + red[2] + red[3];
        }
    } else {
        int idx = (bid - GENE_BLOCKS) * 256 + tid;   // Bn*64 total, exact
        int b = idx >> 6, l = idx & 63;
        int s = ind_x[b];
        vBg[idx] = f2bf(softplus_precise(V[l * Sn + s]));
        if (idx < Bn) {
            int s2 = ind_x[idx];
            v64[idx] = softplus_precise(V[Ln * Sn + s2]);
        }
    }
}

// ---------- main kernel: byte-identical to the 394us-verified champion ----------
//
// term = lgamma(x+r) - lgamma(r) - lgamma(x+1) + x*lsp + r*lsn
//      ~= (s-0.5)ln s - (r-0.5)ln r + x*(lsp-1) + r*lsn - lfact[x],  s = r+x

__global__ __launch_bounds__(256) void main_kernel(
    const int*            __restrict__ x,
    const unsigned short* __restrict__ rhB,
    const unsigned short* __restrict__ vBg,
    const float*          __restrict__ v64,
    const float*          __restrict__ lsp1g,
    const float*          __restrict__ lsng,
    const float*          __restrict__ epsg,
    float*                __restrict__ partial) {
    __shared__ __align__(16) unsigned short sA[64][72];   // v tile [b][l]
    __shared__ __align__(16) unsigned short sB[64][72];   // rh tile [g][l]
    __shared__ float sv64[64];
    __shared__ float sLsp1[64], sLsn[64], sEps[64];
    __shared__ float lfact[100];
    __shared__ float pred[64];

    const int tid = threadIdx.x;
    const int g0 = blockIdx.x * 64;
    const int b0 = blockIdx.y * 64;

    {   // staging: FULL 64x64 tile = 8192B each; 256 thr x 16B x 2 row-passes
        int row = tid >> 3;          // 0..31
        int c   = (tid & 7) * 8;     // 0..56 step 8 (shorts)
        *(uint4*)&sA[row][c]      = *(const uint4*)&vBg[(b0 + row) * 64 + c];
        *(uint4*)&sA[row + 32][c] = *(const uint4*)&vBg[(b0 + row + 32) * 64 + c];
        *(uint4*)&sB[row][c]      = *(const uint4*)&rhB[(g0 + row) * 64 + c];
        *(uint4*)&sB[row + 32][c] = *(const uint4*)&rhB[(g0 + row + 32) * 64 + c];
    }
    if (tid < 64) {
        sv64[tid]  = v64[b0 + tid];
        sLsp1[tid] = lsp1g[g0 + tid];
        sLsn[tid]  = lsng[g0 + tid];
        sEps[tid]  = epsg[g0 + tid];
    }
    if (tid < 100) lfact[tid] = lgamma_pos8((float)tid + 1.0f);

    const int wave = tid >> 6, lane = tid & 63;
    const int quad = lane >> 4, ln = lane & 15;
    const int mrow  = wave * 16 + ln;              // A-fragment m index
    const int brow0 = b0 + wave * 16 + quad * 4;   // C rows for this lane (4 regs)

    // prefetch x tile: 16 dwords/thread (overlaps with LDS + MFMA)
    int xv[4][4];
    #pragma unroll
    for (int nb = 0; nb < 4; nb++) {
        int g = g0 + nb * 16 + ln;
        #pragma unroll
        for (int r = 0; r < 4; r++)
            xv[nb][r] = x[(size_t)(brow0 + r) * Gn + g];
    }

    f32x4 acc[4];
    #pragma unroll
    for (int nb = 0; nb < 4; nb++) acc[nb] = (f32x4){0.f, 0.f, 0.f, 0.f};

    __syncthreads();

    // K=64 in two MFMA steps; wave handles m-block=wave, all 4 n-blocks
    #pragma unroll
    for (int kb = 0; kb < 2; kb++) {
        bf16x8 af = *(const bf16x8*)&sA[mrow][kb * 32 + quad * 8];
        #pragma unroll
        for (int nb = 0; nb < 4; nb++) {
            bf16x8 bfr = *(const bf16x8*)&sB[nb * 16 + ln][kb * 32 + quad * 8];
            acc[nb] = __builtin_amdgcn_mfma_f32_16x16x32_bf16(af, bfr, acc[nb], 0, 0, 0);
        }
    }

    float vvr[4];
    #pragma unroll
    for (int r = 0; r < 4; r++) vvr[r] = sv64[wave * 16 + quad * 4 + r];

    float rowpart[4] = {0.f, 0.f, 0.f, 0.f};
    #pragma unroll
    for (int nb = 0; nb < 4; nb++) {
        const float lsp1v = sLsp1[nb * 16 + ln];
        const float lsnv  = sLsn[nb * 16 + ln];
        const float ev    = sEps[nb * 16 + ln];
        #pragma unroll
        for (int r = 0; r < 4; r++) {
            const float rr = fmaf(ev, vvr[r], acc[nb][r]);   // + eps*v64, fp32
            const int   xi = xv[nb][r];
            const float xf = (float)xi;
            const float s  = rr + xf;
            float t = fmaf(s - 0.5f, __logf(s), -lfact[xi]);
            t = fmaf(-(rr - 0.5f), __logf(rr), t);
            t = fmaf(xf, lsp1v, t);
            t = fmaf(rr, lsnv, t);
            rowpart[r] += t;
        }
    }

    // reduce over the 16 gene-lanes of each quad; stash per-row partials in LDS,
    // then ONE coalesced 256B store per block (no device atomics)
    #pragma unroll
    for (int r = 0; r < 4; r++) {
        float v = rowpart[r];
        v += __shfl_xor(v, 1, 64);
        v += __shfl_xor(v, 2, 64);
        v += __shfl_xor(v, 4, 64);
        v += __shfl_xor(v, 8, 64);
        if (ln == 0) pred[wave * 16 + quad * 4 + r] = v;
    }
    __syncthreads();
    if (tid < 64) partial[(size_t)blockIdx.x * Bn + b0 + tid] = pred[tid];
}

// fold partial[NGT][4096] -> out[b] (negated); block 0 also finalizes the
// two scalar slots (plain stores -> fully idempotent, no memset required).
__global__ __launch_bounds__(256) void reduce_kernel(const float* __restrict__ partial,
                                                     const float* __restrict__ prior_part,
                                                     float* __restrict__ out) {
    int b = blockIdx.x * 256 + threadIdx.x;
    float s0 = 0.f, s1 = 0.f, s2 = 0.f, s3 = 0.f, s4 = 0.f;
    for (int i = 0; i < NGT; i += 5) {
        s0 += partial[(size_t)(i + 0) * Bn + b];
        s1 += partial[(size_t)(i + 1) * Bn + b];
        s2 += partial[(size_t)(i + 2) * Bn + b];
        s3 += partial[(size_t)(i + 3) * Bn + b];
        s4 += partial[(size_t)(i + 4) * Bn + b];
    }
    out[b] = -(s0 + s1 + s2 + s3 + s4);

    if (blockIdx.x == 0) {
        int tid = threadIdx.x;
        if (tid < 64) {   // wave 0: fold the 64 prior partials
            float s = prior_part[tid];
            #pragma unroll
            for (int off = 32; off; off >>= 1) s += __shfl_xor(s, off, 64);
            if (tid == 0) {
                out[Bn]     = 0.0f;   // second ref output is literal 0
                out[Bn + 1] = s;      // -sum log N(eta;0,1)
            }
        }
    }
}

// ---------- launch: 3 dispatches total (was 6) ----------

extern "C" void kernel_launch(void* const* d_in, const int* in_sizes, int n_in,
                              void* d_out, int out_size, void* d_ws, size_t ws_size,
                              hipStream_t stream) {
    const int*   x     = (const int*)d_in[0];
    const int*   ind_x = (const int*)d_in[2];
    const float* W     = (const float*)d_in[3];
    const float* px_o  = (const float*)d_in[4];
    const float* eta   = (const float*)d_in[5];
    const float* V     = (const float*)d_in[6];
    const float* beta  = (const float*)d_in[7];
    float* out = (float*)d_out;

    // ws layout (bytes):
    char* wsb = (char*)d_ws;
    unsigned short* rhB   = (unsigned short*)(wsb);                   // Gn*64*2 = 2,048,000
    unsigned short* vBg   = (unsigned short*)(wsb + 2048000);         // Bn*64*2 =   524,288
    float*          v64   = (float*)(wsb + 2572288);                  // Bn*4    =    16,384
    float*          lsp1  = (float*)(wsb + 2588672);                  // Gn*4
    float*          lsn   = (float*)(wsb + 2652672);
    float*          eps   = (float*)(wsb + 2716672);
    float*          part  = (float*)(wsb + 2780672);                  // NGT*Bn*4 = 4,096,000
    float*          prio  = (float*)(wsb + 6876672);                  // 64*4 = 256

    prep_fused<<<GENE_BLOCKS + SPOT_BLOCKS, 256, 0, stream>>>(
        W, px_o, eta, beta, V, ind_x, rhB, lsp1, lsn, eps, vBg, v64, prio);

    dim3 grid(Gn / 64, Bn / 64);   // 250 x 64, gt-fastest (verified ordering)
    main_kernel<<<grid, 256, 0, stream>>>(x, rhB, vBg, v64, lsp1, lsn, eps, part);

    reduce_kernel<<<Bn / 256, 256, 0, stream>>>(part, prio, out);
}